// Round 1
// baseline (1735.048 us; speedup 1.0000x reference)
//
#include <hip/hip_runtime.h>
#include <hip/hip_bf16.h>
#include <math.h>

typedef __hip_bfloat16 bf16;
typedef __attribute__((ext_vector_type(4))) float f32x4;
typedef __attribute__((ext_vector_type(8))) short short8;

constexpr int Bc = 2, Tc = 1024, Dc = 1024, Hc = 16, Lc = 4, MLPc = 4096, Vc = 32000, HDc = 64;

__device__ __forceinline__ unsigned short f2bu(float f) {
    __hip_bfloat16 h = __float2bfloat16(f);
    unsigned short u;
    __builtin_memcpy(&u, &h, 2);
    return u;
}

enum { EPI_BIAS_BF16 = 0, EPI_GELU = 1, EPI_RESADD = 2, EPI_F32 = 3, EPI_SCORES = 4, EPI_ATTNOUT = 5 };

// C[M,N] = A[M,K](bf16) @ B[N,K]^T (+bias) with per-EPI epilogue.
// Grid: (N/BN, M/BM, batches). 256 threads = 4 waves in 2x2, each wave (BM/2)x(BN/2).
template <int BM, int BN, int BK, int EPI, typename TB>
__global__ __launch_bounds__(256) void gemm_bt(
    const bf16* __restrict__ A, int lda, long sA,
    const TB* __restrict__ Bm, int ldb, long sB,
    void* __restrict__ Cv, int ldc, long sC,
    const float* __restrict__ bias, int K, float scale)
{
    constexpr int BKP = BK + 8;
    __shared__ bf16 As[BM][BKP];
    __shared__ bf16 Bs[BN][BKP];

    const int tid = threadIdx.x;
    const int lane = tid & 63;
    const int w = tid >> 6;
    const int wm = w >> 1, wn = w & 1;
    constexpr int WM = BM / 2, WN = BN / 2;
    constexpr int FM = WM / 16, FN = WN / 16;

    const int z = blockIdx.z;
    const int bx = blockIdx.x, by = blockIdx.y;
    const bf16* Ab = A + (size_t)z * sA + (size_t)by * BM * lda;
    const TB* Bb = Bm + (size_t)z * sB + (size_t)bx * BN * ldb;

    f32x4 acc[FM][FN];
#pragma unroll
    for (int i = 0; i < FM; i++)
#pragma unroll
        for (int j = 0; j < FN; j++) acc[i][j] = (f32x4){0.f, 0.f, 0.f, 0.f};

    const int lr = lane & 15, lq = lane >> 4;

    for (int k0 = 0; k0 < K; k0 += BK) {
        // ---- stage A (bf16) ----
        constexpr int AC = (BM * BK) / (256 * 8);
#pragma unroll
        for (int i = 0; i < AC; i++) {
            int c = tid + i * 256;
            int row = c / (BK / 8);
            int kc = (c % (BK / 8)) * 8;
            int4 v = *reinterpret_cast<const int4*>(Ab + (size_t)row * lda + k0 + kc);
            *reinterpret_cast<int4*>(&As[row][kc]) = v;
        }
        // ---- stage B ----
        if constexpr (sizeof(TB) == 2) {
            constexpr int BC = (BN * BK) / (256 * 8);
#pragma unroll
            for (int i = 0; i < BC; i++) {
                int c = tid + i * 256;
                int row = c / (BK / 8);
                int kc = (c % (BK / 8)) * 8;
                int4 v = *reinterpret_cast<const int4*>(Bb + (size_t)row * ldb + k0 + kc);
                *reinterpret_cast<int4*>(&Bs[row][kc]) = v;
            }
        } else {
            constexpr int BC = (BN * BK) / (256 * 4);
#pragma unroll
            for (int i = 0; i < BC; i++) {
                int c = tid + i * 256;
                int row = c / (BK / 4);
                int kc = (c % (BK / 4)) * 4;
                float4 v = *reinterpret_cast<const float4*>(Bb + (size_t)row * ldb + k0 + kc);
                unsigned long long p = (unsigned long long)f2bu(v.x) |
                                       ((unsigned long long)f2bu(v.y) << 16) |
                                       ((unsigned long long)f2bu(v.z) << 32) |
                                       ((unsigned long long)f2bu(v.w) << 48);
                *reinterpret_cast<unsigned long long*>(&Bs[row][kc]) = p;
            }
        }
        __syncthreads();

#pragma unroll
        for (int kk = 0; kk < BK / 32; kk++) {
            short8 af[FM], bfr[FN];
#pragma unroll
            for (int i = 0; i < FM; i++)
                af[i] = *reinterpret_cast<const short8*>(&As[wm * WM + i * 16 + lr][kk * 32 + lq * 8]);
#pragma unroll
            for (int j = 0; j < FN; j++)
                bfr[j] = *reinterpret_cast<const short8*>(&Bs[wn * WN + j * 16 + lr][kk * 32 + lq * 8]);
#pragma unroll
            for (int i = 0; i < FM; i++)
#pragma unroll
                for (int j = 0; j < FN; j++)
                    acc[i][j] = __builtin_amdgcn_mfma_f32_16x16x32_bf16(af[i], bfr[j], acc[i][j], 0, 0, 0);
        }
        __syncthreads();
    }

    // ---- epilogue ----
#pragma unroll
    for (int i = 0; i < FM; i++) {
#pragma unroll
        for (int j = 0; j < FN; j++) {
#pragma unroll
            for (int r = 0; r < 4; r++) {
                int row = by * BM + wm * WM + i * 16 + lq * 4 + r;
                int col = bx * BN + wn * WN + j * 16 + lr;
                float v = acc[i][j][r];
                if constexpr (EPI == EPI_BIAS_BF16) {
                    v += bias[col];
                    ((bf16*)Cv)[(size_t)row * ldc + col] = __float2bfloat16(v);
                } else if constexpr (EPI == EPI_GELU) {
                    v += bias[col];
                    v = 0.5f * v * (1.0f + erff(v * 0.70710678118f));
                    ((bf16*)Cv)[(size_t)row * ldc + col] = __float2bfloat16(v);
                } else if constexpr (EPI == EPI_RESADD) {
                    float* C = (float*)Cv;
                    size_t idx = (size_t)row * ldc + col;
                    C[idx] += v + bias[col];
                } else if constexpr (EPI == EPI_F32) {
                    ((float*)Cv)[(size_t)row * ldc + col] = v;
                } else if constexpr (EPI == EPI_SCORES) {
                    int h = z & (Hc - 1);
                    float slope = exp2f(-0.5f * (float)(h + 1));
                    float out = (col > row) ? -1e30f : (v * scale - (float)(row - col) * slope);
                    ((float*)Cv)[(size_t)z * sC + (size_t)row * ldc + col] = out;
                } else if constexpr (EPI == EPI_ATTNOUT) {
                    int b = z >> 4, h = z & 15;
                    size_t idx = (size_t)b * Tc * Dc + (size_t)row * Dc + h * HDc + col;
                    ((bf16*)Cv)[idx] = __float2bfloat16(v);
                }
            }
        }
    }
}

__global__ __launch_bounds__(256) void embed_kernel(const int* __restrict__ ids,
                                                    const float* __restrict__ wte,
                                                    float* __restrict__ x) {
    int row = blockIdx.x;
    int t = threadIdx.x;
    int id = ids[row];
    reinterpret_cast<float4*>(x + (size_t)row * Dc)[t] =
        reinterpret_cast<const float4*>(wte + (size_t)id * Dc)[t];
}

__global__ __launch_bounds__(256) void ln_kernel(const float* __restrict__ x,
                                                 const float* __restrict__ g,
                                                 const float* __restrict__ b,
                                                 bf16* __restrict__ out) {
    int row = blockIdx.x;
    int t = threadIdx.x;
    const float4 v = reinterpret_cast<const float4*>(x + (size_t)row * Dc)[t];
    float s = v.x + v.y + v.z + v.w;
    float s2 = v.x * v.x + v.y * v.y + v.z * v.z + v.w * v.w;
#pragma unroll
    for (int o = 32; o > 0; o >>= 1) {
        s += __shfl_down(s, o);
        s2 += __shfl_down(s2, o);
    }
    __shared__ float sm[8];
    int wid = t >> 6, ln = t & 63;
    if (ln == 0) { sm[wid] = s; sm[4 + wid] = s2; }
    __syncthreads();
    if (t == 0) {
        float ts = sm[0] + sm[1] + sm[2] + sm[3];
        float ts2 = sm[4] + sm[5] + sm[6] + sm[7];
        sm[0] = ts; sm[4] = ts2;
    }
    __syncthreads();
    float mean = sm[0] * (1.0f / Dc);
    float var = sm[4] * (1.0f / Dc) - mean * mean;
    float rstd = rsqrtf(var + 1e-5f);
    int c0 = t * 4;
    float vv[4] = {v.x, v.y, v.z, v.w};
    unsigned long long p = 0;
#pragma unroll
    for (int j = 0; j < 4; j++) {
        float val = (vv[j] - mean) * rstd * g[c0 + j] + b[c0 + j];
        p |= (unsigned long long)f2bu(val) << (16 * j);
    }
    *reinterpret_cast<unsigned long long*>(out + (size_t)row * Dc + c0) = p;
}

__global__ __launch_bounds__(256) void unpack_qk(const bf16* __restrict__ qkv,
                                                 bf16* __restrict__ q,
                                                 bf16* __restrict__ k) {
    int idx = blockIdx.x * 256 + threadIdx.x;   // over B*T*D/8
    int bt = idx / 128;                          // D/8 = 128 chunks per row
    int c = idx % 128;
    int b = bt / Tc, t = bt % Tc;
    int h = c >> 3;
    int hd = (c & 7) * 8;
    size_t dst = (((size_t)(b * Hc + h) * Tc + t) * HDc + hd) / 8;
    const int4* src = reinterpret_cast<const int4*>(qkv + (size_t)bt * 3 * Dc);
    reinterpret_cast<int4*>(q)[dst] = src[c];
    reinterpret_cast<int4*>(k)[dst] = src[128 + c];
}

__global__ __launch_bounds__(256) void unpack_vt(const bf16* __restrict__ qkv,
                                                 bf16* __restrict__ vt) {
    int idx = blockIdx.x * 256 + threadIdx.x;   // over B*H*HD*T, t fastest
    int t = idx & (Tc - 1);
    int rest = idx >> 10;
    int hd = rest & 63;
    int zh = rest >> 6;                          // b*H + h
    int b = zh >> 4, h = zh & 15;
    vt[idx] = qkv[((size_t)(b * Tc + t)) * 3 * Dc + 2 * Dc + h * HDc + hd];
}

__global__ __launch_bounds__(256) void softmax_kernel(const float* __restrict__ S,
                                                      bf16* __restrict__ P) {
    size_t row = blockIdx.x;  // B*H*T rows
    int t = threadIdx.x;
    const float4 v = reinterpret_cast<const float4*>(S + row * Tc)[t];
    float mx = fmaxf(fmaxf(v.x, v.y), fmaxf(v.z, v.w));
#pragma unroll
    for (int o = 32; o > 0; o >>= 1) mx = fmaxf(mx, __shfl_down(mx, o));
    __shared__ float sm[8];
    int wid = t >> 6, ln = t & 63;
    if (ln == 0) sm[wid] = mx;
    __syncthreads();
    if (t == 0) sm[0] = fmaxf(fmaxf(sm[0], sm[1]), fmaxf(sm[2], sm[3]));
    __syncthreads();
    mx = sm[0];
    float e0 = expf(v.x - mx), e1 = expf(v.y - mx), e2 = expf(v.z - mx), e3 = expf(v.w - mx);
    float s = e0 + e1 + e2 + e3;
#pragma unroll
    for (int o = 32; o > 0; o >>= 1) s += __shfl_down(s, o);
    if (ln == 0) sm[4 + wid] = s;
    __syncthreads();
    if (t == 0) sm[4] = sm[4] + sm[5] + sm[6] + sm[7];
    __syncthreads();
    float inv = 1.0f / sm[4];
    unsigned long long p = (unsigned long long)f2bu(e0 * inv) |
                           ((unsigned long long)f2bu(e1 * inv) << 16) |
                           ((unsigned long long)f2bu(e2 * inv) << 32) |
                           ((unsigned long long)f2bu(e3 * inv) << 48);
    *reinterpret_cast<unsigned long long*>(P + row * Tc + t * 4) = p;
}

extern "C" void kernel_launch(void* const* d_in, const int* in_sizes, int n_in,
                              void* d_out, int out_size, void* d_ws, size_t ws_size,
                              hipStream_t stream) {
    const int* ids = (const int*)d_in[0];
    const float* wte = (const float*)d_in[1];
    const float* ln1g = (const float*)d_in[2];
    const float* ln1b = (const float*)d_in[3];
    const float* attw = (const float*)d_in[4];
    const float* attb = (const float*)d_in[5];
    const float* projw = (const float*)d_in[6];
    const float* projb = (const float*)d_in[7];
    const float* ln2g = (const float*)d_in[8];
    const float* ln2b = (const float*)d_in[9];
    const float* fcw = (const float*)d_in[10];
    const float* fcb = (const float*)d_in[11];
    const float* fc2w = (const float*)d_in[12];
    const float* fc2b = (const float*)d_in[13];
    const float* lnfg = (const float*)d_in[14];
    const float* lnfb = (const float*)d_in[15];
    const float* lmw = (const float*)d_in[16];

    const int M = Bc * Tc;  // 2048
    char* ws = (char*)d_ws;
    float* x = (float*)ws;   ws += (size_t)M * Dc * 4;
    bf16* h = (bf16*)ws;     ws += (size_t)M * Dc * 2;
    bf16* qkv = (bf16*)ws;   ws += (size_t)M * 3 * Dc * 2;
    bf16* q = (bf16*)ws;     ws += (size_t)Bc * Hc * Tc * HDc * 2;
    bf16* kb = (bf16*)ws;    ws += (size_t)Bc * Hc * Tc * HDc * 2;
    bf16* vt = (bf16*)ws;    ws += (size_t)Bc * Hc * Tc * HDc * 2;
    bf16* y = (bf16*)ws;     ws += (size_t)M * Dc * 2;
    bf16* mlp = (bf16*)ws;   ws += (size_t)M * MLPc * 2;

    // S (fp32) and P (bf16) live in d_out; overwritten by the final lm_head GEMM.
    float* S = (float*)d_out;
    bf16* P = (bf16*)((char*)d_out + (size_t)Bc * Hc * Tc * Tc * 4);

    const long sQ = (long)Tc * HDc;
    const long sS = (long)Tc * Tc;

    embed_kernel<<<M, 256, 0, stream>>>(ids, wte, x);

    for (int l = 0; l < Lc; l++) {
        ln_kernel<<<M, 256, 0, stream>>>(x, ln1g + l * Dc, ln1b + l * Dc, h);

        gemm_bt<128, 128, 64, EPI_BIAS_BF16, float>
            <<<dim3(3 * Dc / 128, M / 128, 1), 256, 0, stream>>>(
                h, Dc, 0, attw + (size_t)l * 3 * Dc * Dc, Dc, 0,
                qkv, 3 * Dc, 0, attb + l * 3 * Dc, Dc, 1.0f);

        unpack_qk<<<(M * Dc / 8) / 256, 256, 0, stream>>>(qkv, q, kb);
        unpack_vt<<<(Bc * Hc * HDc * Tc) / 256, 256, 0, stream>>>(qkv, vt);

        gemm_bt<128, 128, 64, EPI_SCORES, bf16>
            <<<dim3(Tc / 128, Tc / 128, Bc * Hc), 256, 0, stream>>>(
                q, HDc, sQ, kb, HDc, sQ, S, Tc, sS, nullptr, HDc, 0.125f);

        softmax_kernel<<<Bc * Hc * Tc, 256, 0, stream>>>(S, P);

        gemm_bt<128, 64, 64, EPI_ATTNOUT, bf16>
            <<<dim3(1, Tc / 128, Bc * Hc), 256, 0, stream>>>(
                P, Tc, sS, vt, Tc, sQ, y, 0, 0, nullptr, Tc, 1.0f);

        gemm_bt<128, 128, 64, EPI_RESADD, float>
            <<<dim3(Dc / 128, M / 128, 1), 256, 0, stream>>>(
                y, Dc, 0, projw + (size_t)l * Dc * Dc, Dc, 0,
                x, Dc, 0, projb + l * Dc, Dc, 1.0f);

        ln_kernel<<<M, 256, 0, stream>>>(x, ln2g + l * Dc, ln2b + l * Dc, h);

        gemm_bt<128, 128, 64, EPI_GELU, float>
            <<<dim3(MLPc / 128, M / 128, 1), 256, 0, stream>>>(
                h, Dc, 0, fcw + (size_t)l * MLPc * Dc, Dc, 0,
                mlp, MLPc, 0, fcb + l * MLPc, Dc, 1.0f);

        gemm_bt<128, 128, 64, EPI_RESADD, float>
            <<<dim3(Dc / 128, M / 128, 1), 256, 0, stream>>>(
                mlp, MLPc, 0, fc2w + (size_t)l * Dc * MLPc, MLPc, 0,
                x, Dc, 0, fc2b + l * Dc, MLPc, 1.0f);
    }

    ln_kernel<<<M, 256, 0, stream>>>(x, lnfg, lnfb, h);

    gemm_bt<128, 128, 64, EPI_F32, float>
        <<<dim3(Vc / 128, M / 128, 1), 256, 0, stream>>>(
            h, Dc, 0, lmw, Dc, 0, (float*)d_out, Vc, 0, nullptr, Dc, 1.0f);
}

// Round 2
// 1668.287 us; speedup vs baseline: 1.0400x; 1.0400x over previous
//
#include <hip/hip_runtime.h>
#include <hip/hip_bf16.h>
#include <math.h>

typedef __hip_bfloat16 bf16;
typedef __attribute__((ext_vector_type(4))) float f32x4;
typedef __attribute__((ext_vector_type(8))) short short8;

constexpr int Bc = 2, Tc = 1024, Dc = 1024, Hc = 16, Lc = 4, MLPc = 4096, Vc = 32000, HDc = 64;

__device__ __forceinline__ unsigned short f2bu(float f) {
    __hip_bfloat16 h = __float2bfloat16(f);
    unsigned short u;
    __builtin_memcpy(&u, &h, 2);
    return u;
}

__device__ __forceinline__ void gl2lds16(const bf16* g, bf16* l) {
    __builtin_amdgcn_global_load_lds(
        (const __attribute__((address_space(1))) void*)g,
        (__attribute__((address_space(3))) void*)l, 16, 0, 0);
}

enum { EPI_BIAS_BF16 = 0, EPI_GELU = 1, EPI_RESADD = 2, EPI_F32 = 3, EPI_SCORES = 4, EPI_ATTNOUT = 5 };

template <int EPI>
__device__ __forceinline__ void epi_store(float v, int row, int col, void* Cv,
                                          int ldc, long sC, int z,
                                          const float* bias, float scale) {
    if constexpr (EPI == EPI_BIAS_BF16) {
        v += bias[col];
        ((bf16*)Cv)[(size_t)row * ldc + col] = __float2bfloat16(v);
    } else if constexpr (EPI == EPI_GELU) {
        v += bias[col];
        v = 0.5f * v * (1.0f + erff(v * 0.70710678118f));
        ((bf16*)Cv)[(size_t)row * ldc + col] = __float2bfloat16(v);
    } else if constexpr (EPI == EPI_RESADD) {
        float* C = (float*)Cv;
        size_t idx = (size_t)row * ldc + col;
        C[idx] += v + bias[col];
    } else if constexpr (EPI == EPI_F32) {
        ((float*)Cv)[(size_t)row * ldc + col] = v;
    } else if constexpr (EPI == EPI_SCORES) {
        int h = z & (Hc - 1);
        float slope = exp2f(-0.5f * (float)(h + 1));
        float out = (col > row) ? -1e30f : (v * scale - (float)(row - col) * slope);
        ((float*)Cv)[(size_t)z * sC + (size_t)row * ldc + col] = out;
    } else if constexpr (EPI == EPI_ATTNOUT) {
        int b = z >> 4, h = z & 15;
        size_t idx = (size_t)b * Tc * Dc + (size_t)row * Dc + h * HDc + col;
        ((bf16*)Cv)[idx] = __float2bfloat16(v);
    }
}

// ---------- fast path: A,B both bf16, global_load_lds staging (m97 structure) ----------
template <int BM, int BN, int BK, int EPI>
__global__ __launch_bounds__(256) void gemm_fast(
    const bf16* __restrict__ A, int lda, long sA,
    const bf16* __restrict__ Bm, int ldb, long sB,
    void* __restrict__ Cv, int ldc, long sC,
    const float* __restrict__ bias, int K, float scale)
{
    static_assert(BK == 64, "staging geometry assumes BK=64");
    __shared__ alignas(16) bf16 As[BM][BK];
    __shared__ alignas(16) bf16 Bs[BN][BK];

    const int tid = threadIdx.x;
    const int lane = tid & 63;
    const int w = tid >> 6;
    const int wm = w >> 1, wn = w & 1;
    constexpr int WM = BM / 2, WN = BN / 2;
    constexpr int FM = WM / 16, FN = WN / 16;
    constexpr int RPI = 512 / BK;           // rows covered by one wave-instr (8)
    constexpr int AI = BM / (4 * RPI);      // A stage instrs per wave
    constexpr int BI = BN / (4 * RPI);      // B stage instrs per wave

    const int z = blockIdx.z;
    const int bx = blockIdx.x, by = blockIdx.y;
    const bf16* Ab = A + (size_t)z * sA + (size_t)by * BM * lda;
    const bf16* Bb = Bm + (size_t)z * sB + (size_t)bx * BN * ldb;

    const int sr = lane >> 3;           // 0..7 sub-row within an instr
    const int sc = (lane & 7) * 8;      // element col within row
    const int lr = lane & 15, lq = lane >> 4;

    f32x4 acc[FM][FN];
#pragma unroll
    for (int i = 0; i < FM; i++)
#pragma unroll
        for (int j = 0; j < FN; j++) acc[i][j] = (f32x4){0.f, 0.f, 0.f, 0.f};

    for (int k0 = 0; k0 < K; k0 += BK) {
#pragma unroll
        for (int i = 0; i < AI; i++) {
            int row = (w * AI + i) * RPI;   // wave-uniform
            gl2lds16(Ab + (size_t)(row + sr) * lda + k0 + sc, &As[row][0]);
        }
#pragma unroll
        for (int i = 0; i < BI; i++) {
            int row = (w * BI + i) * RPI;
            gl2lds16(Bb + (size_t)(row + sr) * ldb + k0 + sc, &Bs[row][0]);
        }
        __syncthreads();

#pragma unroll
        for (int kk = 0; kk < BK / 32; kk++) {
            short8 af[FM], bfr[FN];
#pragma unroll
            for (int i = 0; i < FM; i++)
                af[i] = *reinterpret_cast<const short8*>(&As[wm * WM + i * 16 + lr][kk * 32 + lq * 8]);
#pragma unroll
            for (int j = 0; j < FN; j++)
                bfr[j] = *reinterpret_cast<const short8*>(&Bs[wn * WN + j * 16 + lr][kk * 32 + lq * 8]);
#pragma unroll
            for (int i = 0; i < FM; i++)
#pragma unroll
                for (int j = 0; j < FN; j++)
                    acc[i][j] = __builtin_amdgcn_mfma_f32_16x16x32_bf16(af[i], bfr[j], acc[i][j], 0, 0, 0);
        }
        __syncthreads();
    }

#pragma unroll
    for (int i = 0; i < FM; i++)
#pragma unroll
        for (int j = 0; j < FN; j++)
#pragma unroll
            for (int r = 0; r < 4; r++) {
                int row = by * BM + wm * WM + i * 16 + lq * 4 + r;
                int col = bx * BN + wn * WN + j * 16 + lr;
                epi_store<EPI>(acc[i][j][r], row, col, Cv, ldc, sC, z, bias, scale);
            }
}

// ---------- slow path: B fp32 with in-flight conversion (round-1, fallback) ----------
template <int BM, int BN, int BK, int EPI>
__global__ __launch_bounds__(256) void gemm_bt_f32(
    const bf16* __restrict__ A, int lda, long sA,
    const float* __restrict__ Bm, int ldb, long sB,
    void* __restrict__ Cv, int ldc, long sC,
    const float* __restrict__ bias, int K, float scale)
{
    constexpr int BKP = BK + 8;
    __shared__ bf16 As[BM][BKP];
    __shared__ bf16 Bs[BN][BKP];

    const int tid = threadIdx.x;
    const int lane = tid & 63;
    const int w = tid >> 6;
    const int wm = w >> 1, wn = w & 1;
    constexpr int WM = BM / 2, WN = BN / 2;
    constexpr int FM = WM / 16, FN = WN / 16;

    const int z = blockIdx.z;
    const int bx = blockIdx.x, by = blockIdx.y;
    const bf16* Ab = A + (size_t)z * sA + (size_t)by * BM * lda;
    const float* Bb = Bm + (size_t)z * sB + (size_t)bx * BN * ldb;

    f32x4 acc[FM][FN];
#pragma unroll
    for (int i = 0; i < FM; i++)
#pragma unroll
        for (int j = 0; j < FN; j++) acc[i][j] = (f32x4){0.f, 0.f, 0.f, 0.f};

    const int lr = lane & 15, lq = lane >> 4;

    for (int k0 = 0; k0 < K; k0 += BK) {
        constexpr int AC = (BM * BK) / (256 * 8);
#pragma unroll
        for (int i = 0; i < AC; i++) {
            int c = tid + i * 256;
            int row = c / (BK / 8);
            int kc = (c % (BK / 8)) * 8;
            int4 v = *reinterpret_cast<const int4*>(Ab + (size_t)row * lda + k0 + kc);
            *reinterpret_cast<int4*>(&As[row][kc]) = v;
        }
        constexpr int BC = (BN * BK) / (256 * 4);
#pragma unroll
        for (int i = 0; i < BC; i++) {
            int c = tid + i * 256;
            int row = c / (BK / 4);
            int kc = (c % (BK / 4)) * 4;
            float4 v = *reinterpret_cast<const float4*>(Bb + (size_t)row * ldb + k0 + kc);
            unsigned long long p = (unsigned long long)f2bu(v.x) |
                                   ((unsigned long long)f2bu(v.y) << 16) |
                                   ((unsigned long long)f2bu(v.z) << 32) |
                                   ((unsigned long long)f2bu(v.w) << 48);
            *reinterpret_cast<unsigned long long*>(&Bs[row][kc]) = p;
        }
        __syncthreads();

#pragma unroll
        for (int kk = 0; kk < BK / 32; kk++) {
            short8 af[FM], bfr[FN];
#pragma unroll
            for (int i = 0; i < FM; i++)
                af[i] = *reinterpret_cast<const short8*>(&As[wm * WM + i * 16 + lr][kk * 32 + lq * 8]);
#pragma unroll
            for (int j = 0; j < FN; j++)
                bfr[j] = *reinterpret_cast<const short8*>(&Bs[wn * WN + j * 16 + lr][kk * 32 + lq * 8]);
#pragma unroll
            for (int i = 0; i < FM; i++)
#pragma unroll
                for (int j = 0; j < FN; j++)
                    acc[i][j] = __builtin_amdgcn_mfma_f32_16x16x32_bf16(af[i], bfr[j], acc[i][j], 0, 0, 0);
        }
        __syncthreads();
    }

#pragma unroll
    for (int i = 0; i < FM; i++)
#pragma unroll
        for (int j = 0; j < FN; j++)
#pragma unroll
            for (int r = 0; r < 4; r++) {
                int row = by * BM + wm * WM + i * 16 + lq * 4 + r;
                int col = bx * BN + wn * WN + j * 16 + lr;
                epi_store<EPI>(acc[i][j][r], row, col, Cv, ldc, sC, z, bias, scale);
            }
}

__global__ __launch_bounds__(256) void f2b8(const float* __restrict__ in,
                                            bf16* __restrict__ out, long n) {
    long i = ((long)blockIdx.x * 256 + threadIdx.x) * 8;
    if (i >= n) return;
    float4 a = *reinterpret_cast<const float4*>(in + i);
    float4 b = *reinterpret_cast<const float4*>(in + i + 4);
    unsigned long long p0 = (unsigned long long)f2bu(a.x) |
                            ((unsigned long long)f2bu(a.y) << 16) |
                            ((unsigned long long)f2bu(a.z) << 32) |
                            ((unsigned long long)f2bu(a.w) << 48);
    unsigned long long p1 = (unsigned long long)f2bu(b.x) |
                            ((unsigned long long)f2bu(b.y) << 16) |
                            ((unsigned long long)f2bu(b.z) << 32) |
                            ((unsigned long long)f2bu(b.w) << 48);
    *reinterpret_cast<unsigned long long*>(out + i) = p0;
    *reinterpret_cast<unsigned long long*>(out + i + 4) = p1;
}

__global__ __launch_bounds__(256) void embed_kernel(const int* __restrict__ ids,
                                                    const float* __restrict__ wte,
                                                    float* __restrict__ x) {
    int row = blockIdx.x;
    int t = threadIdx.x;
    int id = ids[row];
    reinterpret_cast<float4*>(x + (size_t)row * Dc)[t] =
        reinterpret_cast<const float4*>(wte + (size_t)id * Dc)[t];
}

__global__ __launch_bounds__(256) void ln_kernel(const float* __restrict__ x,
                                                 const float* __restrict__ g,
                                                 const float* __restrict__ b,
                                                 bf16* __restrict__ out) {
    int row = blockIdx.x;
    int t = threadIdx.x;
    const float4 v = reinterpret_cast<const float4*>(x + (size_t)row * Dc)[t];
    float s = v.x + v.y + v.z + v.w;
    float s2 = v.x * v.x + v.y * v.y + v.z * v.z + v.w * v.w;
#pragma unroll
    for (int o = 32; o > 0; o >>= 1) {
        s += __shfl_down(s, o);
        s2 += __shfl_down(s2, o);
    }
    __shared__ float sm[8];
    int wid = t >> 6, ln = t & 63;
    if (ln == 0) { sm[wid] = s; sm[4 + wid] = s2; }
    __syncthreads();
    if (t == 0) {
        float ts = sm[0] + sm[1] + sm[2] + sm[3];
        float ts2 = sm[4] + sm[5] + sm[6] + sm[7];
        sm[0] = ts; sm[4] = ts2;
    }
    __syncthreads();
    float mean = sm[0] * (1.0f / Dc);
    float var = sm[4] * (1.0f / Dc) - mean * mean;
    float rstd = rsqrtf(var + 1e-5f);
    int c0 = t * 4;
    float vv[4] = {v.x, v.y, v.z, v.w};
    unsigned long long p = 0;
#pragma unroll
    for (int j = 0; j < 4; j++) {
        float val = (vv[j] - mean) * rstd * g[c0 + j] + b[c0 + j];
        p |= (unsigned long long)f2bu(val) << (16 * j);
    }
    *reinterpret_cast<unsigned long long*>(out + (size_t)row * Dc + c0) = p;
}

__global__ __launch_bounds__(256) void unpack_qk(const bf16* __restrict__ qkv,
                                                 bf16* __restrict__ q,
                                                 bf16* __restrict__ k) {
    int idx = blockIdx.x * 256 + threadIdx.x;
    int bt = idx / 128;
    int c = idx % 128;
    int b = bt / Tc, t = bt % Tc;
    int h = c >> 3;
    int hd = (c & 7) * 8;
    size_t dst = (((size_t)(b * Hc + h) * Tc + t) * HDc + hd) / 8;
    const int4* src = reinterpret_cast<const int4*>(qkv + (size_t)bt * 3 * Dc);
    reinterpret_cast<int4*>(q)[dst] = src[c];
    reinterpret_cast<int4*>(k)[dst] = src[128 + c];
}

__global__ __launch_bounds__(256) void unpack_vt(const bf16* __restrict__ qkv,
                                                 bf16* __restrict__ vt) {
    int idx = blockIdx.x * 256 + threadIdx.x;
    int t = idx & (Tc - 1);
    int rest = idx >> 10;
    int hd = rest & 63;
    int zh = rest >> 6;
    int b = zh >> 4, h = zh & 15;
    vt[idx] = qkv[((size_t)(b * Tc + t)) * 3 * Dc + 2 * Dc + h * HDc + hd];
}

__global__ __launch_bounds__(256) void softmax_kernel(const float* __restrict__ S,
                                                      bf16* __restrict__ P) {
    size_t row = blockIdx.x;
    int t = threadIdx.x;
    const float4 v = reinterpret_cast<const float4*>(S + row * Tc)[t];
    float mx = fmaxf(fmaxf(v.x, v.y), fmaxf(v.z, v.w));
#pragma unroll
    for (int o = 32; o > 0; o >>= 1) mx = fmaxf(mx, __shfl_down(mx, o));
    __shared__ float sm[8];
    int wid = t >> 6, ln = t & 63;
    if (ln == 0) sm[wid] = mx;
    __syncthreads();
    if (t == 0) sm[0] = fmaxf(fmaxf(sm[0], sm[1]), fmaxf(sm[2], sm[3]));
    __syncthreads();
    mx = sm[0];
    float e0 = expf(v.x - mx), e1 = expf(v.y - mx), e2 = expf(v.z - mx), e3 = expf(v.w - mx);
    float s = e0 + e1 + e2 + e3;
#pragma unroll
    for (int o = 32; o > 0; o >>= 1) s += __shfl_down(s, o);
    if (ln == 0) sm[4 + wid] = s;
    __syncthreads();
    if (t == 0) sm[4] = sm[4] + sm[5] + sm[6] + sm[7];
    __syncthreads();
    float inv = 1.0f / sm[4];
    unsigned long long p = (unsigned long long)f2bu(e0 * inv) |
                           ((unsigned long long)f2bu(e1 * inv) << 16) |
                           ((unsigned long long)f2bu(e2 * inv) << 32) |
                           ((unsigned long long)f2bu(e3 * inv) << 48);
    *reinterpret_cast<unsigned long long*>(P + row * Tc + t * 4) = p;
}

extern "C" void kernel_launch(void* const* d_in, const int* in_sizes, int n_in,
                              void* d_out, int out_size, void* d_ws, size_t ws_size,
                              hipStream_t stream) {
    const int* ids = (const int*)d_in[0];
    const float* wte = (const float*)d_in[1];
    const float* ln1g = (const float*)d_in[2];
    const float* ln1b = (const float*)d_in[3];
    const float* attw = (const float*)d_in[4];
    const float* attb = (const float*)d_in[5];
    const float* projw = (const float*)d_in[6];
    const float* projb = (const float*)d_in[7];
    const float* ln2g = (const float*)d_in[8];
    const float* ln2b = (const float*)d_in[9];
    const float* fcw = (const float*)d_in[10];
    const float* fcb = (const float*)d_in[11];
    const float* fc2w = (const float*)d_in[12];
    const float* fc2b = (const float*)d_in[13];
    const float* lnfg = (const float*)d_in[14];
    const float* lnfb = (const float*)d_in[15];
    const float* lmw = (const float*)d_in[16];

    const int M = Bc * Tc;  // 2048
    char* ws = (char*)d_ws;
    size_t off = 0;
    auto carve = [&](size_t bytes) { char* p = ws + off; off += (bytes + 255) & ~(size_t)255; return p; };

    float* x = (float*)carve((size_t)M * Dc * 4);
    bf16* h = (bf16*)carve((size_t)M * Dc * 2);
    bf16* qkv = (bf16*)carve((size_t)M * 3 * Dc * 2);
    bf16* q = (bf16*)carve((size_t)Bc * Hc * Tc * HDc * 2);
    bf16* kb = (bf16*)carve((size_t)Bc * Hc * Tc * HDc * 2);
    bf16* vt = (bf16*)carve((size_t)Bc * Hc * Tc * HDc * 2);
    bf16* y = (bf16*)carve((size_t)M * Dc * 2);
    bf16* mlp = (bf16*)carve((size_t)M * MLPc * 2);
    size_t base_end = off;

    const long nWL = (long)3 * Dc * Dc + (long)Dc * Dc + (long)MLPc * Dc + (long)Dc * MLPc;  // 12.58M
    const long nLM = (long)Vc * Dc;  // 32.77M
    bool has_wl = ws_size >= base_end + (size_t)nWL * 2;
    bf16* wl = nullptr;
    if (has_wl) wl = (bf16*)carve((size_t)nWL * 2);
    bool has_wlm = has_wl && ws_size >= off + (size_t)nLM * 2;
    bf16* wlm = nullptr;
    if (has_wlm) wlm = (bf16*)carve((size_t)nLM * 2);

    bf16* aw_b = wl;
    bf16* pw_b = wl ? wl + (size_t)3 * Dc * Dc : nullptr;
    bf16* fw_b = pw_b ? pw_b + (size_t)Dc * Dc : nullptr;
    bf16* f2w_b = fw_b ? fw_b + (size_t)MLPc * Dc : nullptr;

    // S (fp32) and P (bf16) live in d_out; overwritten by the final lm_head GEMM.
    float* S = (float*)d_out;
    bf16* P = (bf16*)((char*)d_out + (size_t)Bc * Hc * Tc * Tc * 4);

    const long sQ = (long)Tc * HDc;
    const long sS = (long)Tc * Tc;

    embed_kernel<<<M, 256, 0, stream>>>(ids, wte, x);

    if (has_wlm)
        f2b8<<<(int)(nLM / 8 / 256), 256, 0, stream>>>(lmw, wlm, nLM);

    for (int l = 0; l < Lc; l++) {
        if (has_wl) {
            f2b8<<<(int)((long)3 * Dc * Dc / 8 / 256), 256, 0, stream>>>(
                attw + (size_t)l * 3 * Dc * Dc, aw_b, (long)3 * Dc * Dc);
            f2b8<<<(int)((long)Dc * Dc / 8 / 256), 256, 0, stream>>>(
                projw + (size_t)l * Dc * Dc, pw_b, (long)Dc * Dc);
            f2b8<<<(int)((long)MLPc * Dc / 8 / 256), 256, 0, stream>>>(
                fcw + (size_t)l * MLPc * Dc, fw_b, (long)MLPc * Dc);
            f2b8<<<(int)((long)Dc * MLPc / 8 / 256), 256, 0, stream>>>(
                fc2w + (size_t)l * Dc * MLPc, f2w_b, (long)Dc * MLPc);
        }

        ln_kernel<<<M, 256, 0, stream>>>(x, ln1g + l * Dc, ln1b + l * Dc, h);

        if (has_wl)
            gemm_fast<128, 128, 64, EPI_BIAS_BF16>
                <<<dim3(3 * Dc / 128, M / 128, 1), 256, 0, stream>>>(
                    h, Dc, 0, aw_b, Dc, 0, qkv, 3 * Dc, 0, attb + l * 3 * Dc, Dc, 1.0f);
        else
            gemm_bt_f32<128, 128, 64, EPI_BIAS_BF16>
                <<<dim3(3 * Dc / 128, M / 128, 1), 256, 0, stream>>>(
                    h, Dc, 0, attw + (size_t)l * 3 * Dc * Dc, Dc, 0,
                    qkv, 3 * Dc, 0, attb + l * 3 * Dc, Dc, 1.0f);

        unpack_qk<<<(M * Dc / 8) / 256, 256, 0, stream>>>(qkv, q, kb);
        unpack_vt<<<(Bc * Hc * HDc * Tc) / 256, 256, 0, stream>>>(qkv, vt);

        gemm_fast<128, 128, 64, EPI_SCORES>
            <<<dim3(Tc / 128, Tc / 128, Bc * Hc), 256, 0, stream>>>(
                q, HDc, sQ, kb, HDc, sQ, S, Tc, sS, nullptr, HDc, 0.125f);

        softmax_kernel<<<Bc * Hc * Tc, 256, 0, stream>>>(S, P);

        gemm_fast<128, 64, 64, EPI_ATTNOUT>
            <<<dim3(1, Tc / 128, Bc * Hc), 256, 0, stream>>>(
                P, Tc, sS, vt, Tc, sQ, y, 0, 0, nullptr, Tc, 1.0f);

        if (has_wl) {
            gemm_fast<128, 128, 64, EPI_RESADD>
                <<<dim3(Dc / 128, M / 128, 1), 256, 0, stream>>>(
                    y, Dc, 0, pw_b, Dc, 0, x, Dc, 0, projb + l * Dc, Dc, 1.0f);

            ln_kernel<<<M, 256, 0, stream>>>(x, ln2g + l * Dc, ln2b + l * Dc, h);

            gemm_fast<128, 128, 64, EPI_GELU>
                <<<dim3(MLPc / 128, M / 128, 1), 256, 0, stream>>>(
                    h, Dc, 0, fw_b, Dc, 0, mlp, MLPc, 0, fcb + l * MLPc, Dc, 1.0f);

            gemm_fast<128, 128, 64, EPI_RESADD>
                <<<dim3(Dc / 128, M / 128, 1), 256, 0, stream>>>(
                    mlp, MLPc, 0, f2w_b, MLPc, 0, x, Dc, 0, fc2b + l * Dc, MLPc, 1.0f);
        } else {
            gemm_bt_f32<128, 128, 64, EPI_RESADD>
                <<<dim3(Dc / 128, M / 128, 1), 256, 0, stream>>>(
                    y, Dc, 0, projw + (size_t)l * Dc * Dc, Dc, 0,
                    x, Dc, 0, projb + l * Dc, Dc, 1.0f);

            ln_kernel<<<M, 256, 0, stream>>>(x, ln2g + l * Dc, ln2b + l * Dc, h);

            gemm_bt_f32<128, 128, 64, EPI_GELU>
                <<<dim3(MLPc / 128, M / 128, 1), 256, 0, stream>>>(
                    h, Dc, 0, fcw + (size_t)l * MLPc * Dc, Dc, 0,
                    mlp, MLPc, 0, fcb + l * MLPc, Dc, 1.0f);

            gemm_bt_f32<128, 128, 64, EPI_RESADD>
                <<<dim3(Dc / 128, M / 128, 1), 256, 0, stream>>>(
                    mlp, MLPc, 0, fc2w + (size_t)l * Dc * MLPc, MLPc, 0,
                    x, Dc, 0, fc2b + l * Dc, MLPc, 1.0f);
        }
    }

    ln_kernel<<<M, 256, 0, stream>>>(x, lnfg, lnfb, h);

    if (has_wlm)
        gemm_fast<128, 128, 64, EPI_F32>
            <<<dim3(Vc / 128, M / 128, 1), 256, 0, stream>>>(
                h, Dc, 0, wlm, Dc, 0, (float*)d_out, Vc, 0, nullptr, Dc, 1.0f);
    else
        gemm_bt_f32<128, 128, 64, EPI_F32>
            <<<dim3(Vc / 128, M / 128, 1), 256, 0, stream>>>(
                h, Dc, 0, lmw, Dc, 0, (float*)d_out, Vc, 0, nullptr, Dc, 1.0f);
}

// Round 3
// 1596.503 us; speedup vs baseline: 1.0868x; 1.0450x over previous
//
#include <hip/hip_runtime.h>
#include <hip/hip_bf16.h>
#include <math.h>

typedef __hip_bfloat16 bf16;
typedef __attribute__((ext_vector_type(4))) float f32x4;
typedef __attribute__((ext_vector_type(8))) short short8;

constexpr int Bc = 2, Tc = 1024, Dc = 1024, Hc = 16, Lc = 4, MLPc = 4096, Vc = 32000, HDc = 64;

__device__ __forceinline__ unsigned short f2bu(float f) {
    __hip_bfloat16 h = __float2bfloat16(f);
    unsigned short u;
    __builtin_memcpy(&u, &h, 2);
    return u;
}

__device__ __forceinline__ void gl2lds16(const bf16* g, bf16* l) {
    __builtin_amdgcn_global_load_lds(
        (const __attribute__((address_space(1))) void*)g,
        (__attribute__((address_space(3))) void*)l, 16, 0, 0);
}

enum { EPI_BIAS_BF16 = 0, EPI_GELU = 1, EPI_RESADD = 2, EPI_F32 = 3, EPI_SCORES = 4, EPI_ATTNOUT = 5 };

template <int EPI>
__device__ __forceinline__ void epi_store(float v, int row, int col, void* Cv,
                                          int ldc, long sC, int z,
                                          const float* bias, float scale) {
    if constexpr (EPI == EPI_BIAS_BF16) {
        v += bias[col];
        ((bf16*)Cv)[(size_t)row * ldc + col] = __float2bfloat16(v);
    } else if constexpr (EPI == EPI_GELU) {
        v += bias[col];
        v = 0.5f * v * (1.0f + erff(v * 0.70710678118f));
        ((bf16*)Cv)[(size_t)row * ldc + col] = __float2bfloat16(v);
    } else if constexpr (EPI == EPI_RESADD) {
        float* C = (float*)Cv;
        size_t idx = (size_t)row * ldc + col;
        C[idx] += v + bias[col];
    } else if constexpr (EPI == EPI_F32) {
        ((float*)Cv)[(size_t)row * ldc + col] = v;
    } else if constexpr (EPI == EPI_SCORES) {
        int h = z & (Hc - 1);
        float slope = exp2f(-0.5f * (float)(h + 1));
        float out = (col > row) ? -1e30f : (v * scale - (float)(row - col) * slope);
        ((float*)Cv)[(size_t)z * sC + (size_t)row * ldc + col] = out;
    } else if constexpr (EPI == EPI_ATTNOUT) {
        int b = z >> 4, h = z & 15;
        size_t idx = (size_t)b * Tc * Dc + (size_t)row * Dc + h * HDc + col;
        ((bf16*)Cv)[idx] = __float2bfloat16(v);
    }
}

// ---------- fast path: A,B bf16, global_load_lds staging, T2 swizzle, optional T1 grid swizzle ----
// SWZG: grid = (M/BM, N/BN); M index fastest + bijective XCD chunking (weight-panel L2 reuse).
// else: grid = (N/BN, M/BM, Z) as before.
template <int BM, int BN, int BK, int EPI, bool SWZG>
__global__ __launch_bounds__(256) void gemm_fast(
    const bf16* __restrict__ A, int lda, long sA,
    const bf16* __restrict__ Bm, int ldb, long sB,
    void* __restrict__ Cv, int ldc, long sC,
    const float* __restrict__ bias, int K, float scale)
{
    static_assert(BK == 64, "staging geometry assumes BK=64");
    __shared__ alignas(16) bf16 As[BM][BK];
    __shared__ alignas(16) bf16 Bs[BN][BK];

    const int tid = threadIdx.x;
    const int lane = tid & 63;
    const int w = tid >> 6;
    const int wm = w >> 1, wn = w & 1;
    constexpr int WM = BM / 2, WN = BN / 2;
    constexpr int FM = WM / 16, FN = WN / 16;
    constexpr int RPI = 512 / BK;           // rows per stage instr (8)
    constexpr int AI = BM / (4 * RPI);
    constexpr int BI = BN / (4 * RPI);

    int im, in;                              // M-panel, N-panel indices
    if constexpr (SWZG) {
        int nwg = gridDim.x * gridDim.y;
        int orig = blockIdx.y * gridDim.x + blockIdx.x;
        int q = nwg >> 3, rr = nwg & 7, xcd = orig & 7, lid = orig >> 3;
        int wg = (xcd < rr ? xcd * (q + 1) : rr * (q + 1) + (xcd - rr) * q) + lid;
        im = wg % gridDim.x;                 // gridDim.x = M/BM (fast: share B-panel)
        in = wg / gridDim.x;
    } else {
        im = blockIdx.y;
        in = blockIdx.x;
    }

    const int z = blockIdx.z;
    const bf16* Ab = A + (size_t)z * sA + (size_t)im * BM * lda;
    const bf16* Bb = Bm + (size_t)z * sB + (size_t)in * BN * ldb;

    const int sr = lane >> 3;                // 0..7 sub-row within a stage instr
    const int scs = (((lane & 7) ^ sr) * 8); // pre-swizzled source column (elements)
    const int lr = lane & 15, lq = lane >> 4;

    f32x4 acc[FM][FN];
#pragma unroll
    for (int i = 0; i < FM; i++)
#pragma unroll
        for (int j = 0; j < FN; j++) acc[i][j] = (f32x4){0.f, 0.f, 0.f, 0.f};

    for (int k0 = 0; k0 < K; k0 += BK) {
#pragma unroll
        for (int i = 0; i < AI; i++) {
            int row = (w * AI + i) * RPI;    // wave-uniform, multiple of 8
            gl2lds16(Ab + (size_t)(row + sr) * lda + k0 + scs, &As[row][0]);
        }
#pragma unroll
        for (int i = 0; i < BI; i++) {
            int row = (w * BI + i) * RPI;
            gl2lds16(Bb + (size_t)(row + sr) * ldb + k0 + scs, &Bs[row][0]);
        }
        __syncthreads();

#pragma unroll
        for (int kk = 0; kk < BK / 32; kk++) {
            short8 af[FM], bfr[FN];
#pragma unroll
            for (int i = 0; i < FM; i++) {
                int r = wm * WM + i * 16 + lr;
                int cb = (kk * 64 + lq * 16) ^ ((r & 7) << 4);
                af[i] = *reinterpret_cast<const short8*>((const char*)As + (size_t)r * (BK * 2) + cb);
            }
#pragma unroll
            for (int j = 0; j < FN; j++) {
                int r = wn * WN + j * 16 + lr;
                int cb = (kk * 64 + lq * 16) ^ ((r & 7) << 4);
                bfr[j] = *reinterpret_cast<const short8*>((const char*)Bs + (size_t)r * (BK * 2) + cb);
            }
#pragma unroll
            for (int i = 0; i < FM; i++)
#pragma unroll
                for (int j = 0; j < FN; j++)
                    acc[i][j] = __builtin_amdgcn_mfma_f32_16x16x32_bf16(af[i], bfr[j], acc[i][j], 0, 0, 0);
        }
        __syncthreads();
    }

#pragma unroll
    for (int i = 0; i < FM; i++)
#pragma unroll
        for (int j = 0; j < FN; j++)
#pragma unroll
            for (int r = 0; r < 4; r++) {
                int row = im * BM + wm * WM + i * 16 + lq * 4 + r;
                int col = in * BN + wn * WN + j * 16 + lr;
                epi_store<EPI>(acc[i][j][r], row, col, Cv, ldc, sC, z, bias, scale);
            }
}

// ---------- slow path: B fp32 in-flight conversion (fallback if ws too small) ----------
template <int BM, int BN, int BK, int EPI>
__global__ __launch_bounds__(256) void gemm_bt_f32(
    const bf16* __restrict__ A, int lda, long sA,
    const float* __restrict__ Bm, int ldb, long sB,
    void* __restrict__ Cv, int ldc, long sC,
    const float* __restrict__ bias, int K, float scale)
{
    constexpr int BKP = BK + 8;
    __shared__ bf16 As[BM][BKP];
    __shared__ bf16 Bs[BN][BKP];

    const int tid = threadIdx.x;
    const int lane = tid & 63;
    const int w = tid >> 6;
    const int wm = w >> 1, wn = w & 1;
    constexpr int WM = BM / 2, WN = BN / 2;
    constexpr int FM = WM / 16, FN = WN / 16;

    const int z = blockIdx.z;
    const int bx = blockIdx.x, by = blockIdx.y;
    const bf16* Ab = A + (size_t)z * sA + (size_t)by * BM * lda;
    const float* Bb = Bm + (size_t)z * sB + (size_t)bx * BN * ldb;

    f32x4 acc[FM][FN];
#pragma unroll
    for (int i = 0; i < FM; i++)
#pragma unroll
        for (int j = 0; j < FN; j++) acc[i][j] = (f32x4){0.f, 0.f, 0.f, 0.f};

    const int lr = lane & 15, lq = lane >> 4;

    for (int k0 = 0; k0 < K; k0 += BK) {
        constexpr int AC = (BM * BK) / (256 * 8);
#pragma unroll
        for (int i = 0; i < AC; i++) {
            int c = tid + i * 256;
            int row = c / (BK / 8);
            int kc = (c % (BK / 8)) * 8;
            int4 v = *reinterpret_cast<const int4*>(Ab + (size_t)row * lda + k0 + kc);
            *reinterpret_cast<int4*>(&As[row][kc]) = v;
        }
        constexpr int BC = (BN * BK) / (256 * 4);
#pragma unroll
        for (int i = 0; i < BC; i++) {
            int c = tid + i * 256;
            int row = c / (BK / 4);
            int kc = (c % (BK / 4)) * 4;
            float4 v = *reinterpret_cast<const float4*>(Bb + (size_t)row * ldb + k0 + kc);
            unsigned long long p = (unsigned long long)f2bu(v.x) |
                                   ((unsigned long long)f2bu(v.y) << 16) |
                                   ((unsigned long long)f2bu(v.z) << 32) |
                                   ((unsigned long long)f2bu(v.w) << 48);
            *reinterpret_cast<unsigned long long*>(&Bs[row][kc]) = p;
        }
        __syncthreads();

#pragma unroll
        for (int kk = 0; kk < BK / 32; kk++) {
            short8 af[FM], bfr[FN];
#pragma unroll
            for (int i = 0; i < FM; i++)
                af[i] = *reinterpret_cast<const short8*>(&As[wm * WM + i * 16 + lr][kk * 32 + lq * 8]);
#pragma unroll
            for (int j = 0; j < FN; j++)
                bfr[j] = *reinterpret_cast<const short8*>(&Bs[wn * WN + j * 16 + lr][kk * 32 + lq * 8]);
#pragma unroll
            for (int i = 0; i < FM; i++)
#pragma unroll
                for (int j = 0; j < FN; j++)
                    acc[i][j] = __builtin_amdgcn_mfma_f32_16x16x32_bf16(af[i], bfr[j], acc[i][j], 0, 0, 0);
        }
        __syncthreads();
    }

#pragma unroll
    for (int i = 0; i < FM; i++)
#pragma unroll
        for (int j = 0; j < FN; j++)
#pragma unroll
            for (int r = 0; r < 4; r++) {
                int row = by * BM + wm * WM + i * 16 + lq * 4 + r;
                int col = bx * BN + wn * WN + j * 16 + lr;
                epi_store<EPI>(acc[i][j][r], row, col, Cv, ldc, sC, z, bias, scale);
            }
}

__global__ __launch_bounds__(256) void f2b8(const float* __restrict__ in,
                                            bf16* __restrict__ out, long n) {
    long i = ((long)blockIdx.x * 256 + threadIdx.x) * 8;
    if (i >= n) return;
    float4 a = *reinterpret_cast<const float4*>(in + i);
    float4 b = *reinterpret_cast<const float4*>(in + i + 4);
    unsigned long long p0 = (unsigned long long)f2bu(a.x) |
                            ((unsigned long long)f2bu(a.y) << 16) |
                            ((unsigned long long)f2bu(a.z) << 32) |
                            ((unsigned long long)f2bu(a.w) << 48);
    unsigned long long p1 = (unsigned long long)f2bu(b.x) |
                            ((unsigned long long)f2bu(b.y) << 16) |
                            ((unsigned long long)f2bu(b.z) << 32) |
                            ((unsigned long long)f2bu(b.w) << 48);
    *reinterpret_cast<unsigned long long*>(out + i) = p0;
    *reinterpret_cast<unsigned long long*>(out + i + 4) = p1;
}

__global__ __launch_bounds__(256) void embed_kernel(const int* __restrict__ ids,
                                                    const float* __restrict__ wte,
                                                    float* __restrict__ x) {
    int row = blockIdx.x;
    int t = threadIdx.x;
    int id = ids[row];
    reinterpret_cast<float4*>(x + (size_t)row * Dc)[t] =
        reinterpret_cast<const float4*>(wte + (size_t)id * Dc)[t];
}

__global__ __launch_bounds__(256) void ln_kernel(const float* __restrict__ x,
                                                 const float* __restrict__ g,
                                                 const float* __restrict__ b,
                                                 bf16* __restrict__ out) {
    int row = blockIdx.x;
    int t = threadIdx.x;
    const float4 v = reinterpret_cast<const float4*>(x + (size_t)row * Dc)[t];
    float s = v.x + v.y + v.z + v.w;
    float s2 = v.x * v.x + v.y * v.y + v.z * v.z + v.w * v.w;
#pragma unroll
    for (int o = 32; o > 0; o >>= 1) {
        s += __shfl_down(s, o);
        s2 += __shfl_down(s2, o);
    }
    __shared__ float sm[8];
    int wid = t >> 6, ln = t & 63;
    if (ln == 0) { sm[wid] = s; sm[4 + wid] = s2; }
    __syncthreads();
    if (t == 0) {
        float ts = sm[0] + sm[1] + sm[2] + sm[3];
        float ts2 = sm[4] + sm[5] + sm[6] + sm[7];
        sm[0] = ts; sm[4] = ts2;
    }
    __syncthreads();
    float mean = sm[0] * (1.0f / Dc);
    float var = sm[4] * (1.0f / Dc) - mean * mean;
    float rstd = rsqrtf(var + 1e-5f);
    int c0 = t * 4;
    float vv[4] = {v.x, v.y, v.z, v.w};
    unsigned long long p = 0;
#pragma unroll
    for (int j = 0; j < 4; j++) {
        float val = (vv[j] - mean) * rstd * g[c0 + j] + b[c0 + j];
        p |= (unsigned long long)f2bu(val) << (16 * j);
    }
    *reinterpret_cast<unsigned long long*>(out + (size_t)row * Dc + c0) = p;
}

__global__ __launch_bounds__(256) void unpack_qk(const bf16* __restrict__ qkv,
                                                 bf16* __restrict__ q,
                                                 bf16* __restrict__ k) {
    int idx = blockIdx.x * 256 + threadIdx.x;
    int bt = idx / 128;
    int c = idx % 128;
    int b = bt / Tc, t = bt % Tc;
    int h = c >> 3;
    int hd = (c & 7) * 8;
    size_t dst = (((size_t)(b * Hc + h) * Tc + t) * HDc + hd) / 8;
    const int4* src = reinterpret_cast<const int4*>(qkv + (size_t)bt * 3 * Dc);
    reinterpret_cast<int4*>(q)[dst] = src[c];
    reinterpret_cast<int4*>(k)[dst] = src[128 + c];
}

__global__ __launch_bounds__(256) void unpack_vt(const bf16* __restrict__ qkv,
                                                 bf16* __restrict__ vt) {
    int idx = blockIdx.x * 256 + threadIdx.x;
    int t = idx & (Tc - 1);
    int rest = idx >> 10;
    int hd = rest & 63;
    int zh = rest >> 6;
    int b = zh >> 4, h = zh & 15;
    vt[idx] = qkv[((size_t)(b * Tc + t)) * 3 * Dc + 2 * Dc + h * HDc + hd];
}

__global__ __launch_bounds__(256) void softmax_kernel(const float* __restrict__ S,
                                                      bf16* __restrict__ P) {
    size_t row = blockIdx.x;
    int t = threadIdx.x;
    const float4 v = reinterpret_cast<const float4*>(S + row * Tc)[t];
    float mx = fmaxf(fmaxf(v.x, v.y), fmaxf(v.z, v.w));
#pragma unroll
    for (int o = 32; o > 0; o >>= 1) mx = fmaxf(mx, __shfl_down(mx, o));
    __shared__ float sm[8];
    int wid = t >> 6, ln = t & 63;
    if (ln == 0) sm[wid] = mx;
    __syncthreads();
    if (t == 0) sm[0] = fmaxf(fmaxf(sm[0], sm[1]), fmaxf(sm[2], sm[3]));
    __syncthreads();
    mx = sm[0];
    float e0 = expf(v.x - mx), e1 = expf(v.y - mx), e2 = expf(v.z - mx), e3 = expf(v.w - mx);
    float s = e0 + e1 + e2 + e3;
#pragma unroll
    for (int o = 32; o > 0; o >>= 1) s += __shfl_down(s, o);
    if (ln == 0) sm[4 + wid] = s;
    __syncthreads();
    if (t == 0) sm[4] = sm[4] + sm[5] + sm[6] + sm[7];
    __syncthreads();
    float inv = 1.0f / sm[4];
    unsigned long long p = (unsigned long long)f2bu(e0 * inv) |
                           ((unsigned long long)f2bu(e1 * inv) << 16) |
                           ((unsigned long long)f2bu(e2 * inv) << 32) |
                           ((unsigned long long)f2bu(e3 * inv) << 48);
    *reinterpret_cast<unsigned long long*>(P + row * Tc + t * 4) = p;
}

extern "C" void kernel_launch(void* const* d_in, const int* in_sizes, int n_in,
                              void* d_out, int out_size, void* d_ws, size_t ws_size,
                              hipStream_t stream) {
    const int* ids = (const int*)d_in[0];
    const float* wte = (const float*)d_in[1];
    const float* ln1g = (const float*)d_in[2];
    const float* ln1b = (const float*)d_in[3];
    const float* attw = (const float*)d_in[4];
    const float* attb = (const float*)d_in[5];
    const float* projw = (const float*)d_in[6];
    const float* projb = (const float*)d_in[7];
    const float* ln2g = (const float*)d_in[8];
    const float* ln2b = (const float*)d_in[9];
    const float* fcw = (const float*)d_in[10];
    const float* fcb = (const float*)d_in[11];
    const float* fc2w = (const float*)d_in[12];
    const float* fc2b = (const float*)d_in[13];
    const float* lnfg = (const float*)d_in[14];
    const float* lnfb = (const float*)d_in[15];
    const float* lmw = (const float*)d_in[16];

    const int M = Bc * Tc;  // 2048
    char* ws = (char*)d_ws;
    size_t off = 0;
    auto carve = [&](size_t bytes) { char* p = ws + off; off += (bytes + 255) & ~(size_t)255; return p; };

    float* x = (float*)carve((size_t)M * Dc * 4);
    bf16* h = (bf16*)carve((size_t)M * Dc * 2);
    bf16* qkv = (bf16*)carve((size_t)M * 3 * Dc * 2);
    bf16* q = (bf16*)carve((size_t)Bc * Hc * Tc * HDc * 2);
    bf16* kb = (bf16*)carve((size_t)Bc * Hc * Tc * HDc * 2);
    bf16* vt = (bf16*)carve((size_t)Bc * Hc * Tc * HDc * 2);
    bf16* y = (bf16*)carve((size_t)M * Dc * 2);
    bf16* mlp = (bf16*)carve((size_t)M * MLPc * 2);
    size_t base_end = off;

    const long nWL = (long)3 * Dc * Dc + (long)Dc * Dc + (long)MLPc * Dc + (long)Dc * MLPc;
    const long nLM = (long)Vc * Dc;
    bool has_wl = ws_size >= base_end + (size_t)nWL * 2;
    bf16* wl = nullptr;
    if (has_wl) wl = (bf16*)carve((size_t)nWL * 2);
    bool has_wlm = has_wl && ws_size >= off + (size_t)nLM * 2;
    bf16* wlm = nullptr;
    if (has_wlm) wlm = (bf16*)carve((size_t)nLM * 2);

    bf16* aw_b = wl;
    bf16* pw_b = wl ? wl + (size_t)3 * Dc * Dc : nullptr;
    bf16* fw_b = pw_b ? pw_b + (size_t)Dc * Dc : nullptr;
    bf16* f2w_b = fw_b ? fw_b + (size_t)MLPc * Dc : nullptr;

    float* S = (float*)d_out;
    bf16* P = (bf16*)((char*)d_out + (size_t)Bc * Hc * Tc * Tc * 4);

    const long sQ = (long)Tc * HDc;
    const long sS = (long)Tc * Tc;

    embed_kernel<<<M, 256, 0, stream>>>(ids, wte, x);

    if (has_wlm)
        f2b8<<<(int)(nLM / 8 / 256), 256, 0, stream>>>(lmw, wlm, nLM);

    for (int l = 0; l < Lc; l++) {
        if (has_wl) {
            f2b8<<<(int)((long)3 * Dc * Dc / 8 / 256), 256, 0, stream>>>(
                attw + (size_t)l * 3 * Dc * Dc, aw_b, (long)3 * Dc * Dc);
            f2b8<<<(int)((long)Dc * Dc / 8 / 256), 256, 0, stream>>>(
                projw + (size_t)l * Dc * Dc, pw_b, (long)Dc * Dc);
            f2b8<<<(int)((long)MLPc * Dc / 8 / 256), 256, 0, stream>>>(
                fcw + (size_t)l * MLPc * Dc, fw_b, (long)MLPc * Dc);
            f2b8<<<(int)((long)Dc * MLPc / 8 / 256), 256, 0, stream>>>(
                fc2w + (size_t)l * Dc * MLPc, f2w_b, (long)Dc * MLPc);
        }

        ln_kernel<<<M, 256, 0, stream>>>(x, ln1g + l * Dc, ln1b + l * Dc, h);

        if (has_wl)
            gemm_fast<128, 128, 64, EPI_BIAS_BF16, true>
                <<<dim3(M / 128, 3 * Dc / 128, 1), 256, 0, stream>>>(
                    h, Dc, 0, aw_b, Dc, 0, qkv, 3 * Dc, 0, attb + l * 3 * Dc, Dc, 1.0f);
        else
            gemm_bt_f32<128, 128, 64, EPI_BIAS_BF16>
                <<<dim3(3 * Dc / 128, M / 128, 1), 256, 0, stream>>>(
                    h, Dc, 0, attw + (size_t)l * 3 * Dc * Dc, Dc, 0,
                    qkv, 3 * Dc, 0, attb + l * 3 * Dc, Dc, 1.0f);

        unpack_qk<<<(M * Dc / 8) / 256, 256, 0, stream>>>(qkv, q, kb);
        unpack_vt<<<(Bc * Hc * HDc * Tc) / 256, 256, 0, stream>>>(qkv, vt);

        gemm_fast<128, 128, 64, EPI_SCORES, false>
            <<<dim3(Tc / 128, Tc / 128, Bc * Hc), 256, 0, stream>>>(
                q, HDc, sQ, kb, HDc, sQ, S, Tc, sS, nullptr, HDc, 0.125f);

        softmax_kernel<<<Bc * Hc * Tc, 256, 0, stream>>>(S, P);

        gemm_fast<128, 64, 64, EPI_ATTNOUT, false>
            <<<dim3(1, Tc / 128, Bc * Hc), 256, 0, stream>>>(
                P, Tc, sS, vt, Tc, sQ, y, 0, 0, nullptr, Tc, 1.0f);

        if (has_wl) {
            gemm_fast<128, 128, 64, EPI_RESADD, true>
                <<<dim3(M / 128, Dc / 128, 1), 256, 0, stream>>>(
                    y, Dc, 0, pw_b, Dc, 0, x, Dc, 0, projb + l * Dc, Dc, 1.0f);

            ln_kernel<<<M, 256, 0, stream>>>(x, ln2g + l * Dc, ln2b + l * Dc, h);

            gemm_fast<128, 128, 64, EPI_GELU, true>
                <<<dim3(M / 128, MLPc / 128, 1), 256, 0, stream>>>(
                    h, Dc, 0, fw_b, Dc, 0, mlp, MLPc, 0, fcb + l * MLPc, Dc, 1.0f);

            gemm_fast<128, 128, 64, EPI_RESADD, true>
                <<<dim3(M / 128, Dc / 128, 1), 256, 0, stream>>>(
                    mlp, MLPc, 0, f2w_b, MLPc, 0, x, Dc, 0, fc2b + l * Dc, MLPc, 1.0f);
        } else {
            gemm_bt_f32<128, 128, 64, EPI_RESADD>
                <<<dim3(Dc / 128, M / 128, 1), 256, 0, stream>>>(
                    y, Dc, 0, projw + (size_t)l * Dc * Dc, Dc, 0,
                    x, Dc, 0, projb + l * Dc, Dc, 1.0f);

            ln_kernel<<<M, 256, 0, stream>>>(x, ln2g + l * Dc, ln2b + l * Dc, h);

            gemm_bt_f32<128, 128, 64, EPI_GELU>
                <<<dim3(MLPc / 128, M / 128, 1), 256, 0, stream>>>(
                    h, Dc, 0, fcw + (size_t)l * MLPc * Dc, Dc, 0,
                    mlp, MLPc, 0, fcb + l * MLPc, Dc, 1.0f);

            gemm_bt_f32<128, 128, 64, EPI_RESADD>
                <<<dim3(Dc / 128, M / 128, 1), 256, 0, stream>>>(
                    mlp, MLPc, 0, fc2w + (size_t)l * Dc * MLPc, MLPc, 0,
                    x, Dc, 0, fc2b + l * Dc, MLPc, 1.0f);
        }
    }

    ln_kernel<<<M, 256, 0, stream>>>(x, lnfg, lnfb, h);

    if (has_wlm)
        gemm_fast<128, 128, 64, EPI_F32, true>
            <<<dim3(M / 128, Vc / 128, 1), 256, 0, stream>>>(
                h, Dc, 0, wlm, Dc, 0, (float*)d_out, Vc, 0, nullptr, Dc, 1.0f);
    else
        gemm_bt_f32<128, 128, 64, EPI_F32>
            <<<dim3(Vc / 128, M / 128, 1), 256, 0, stream>>>(
                h, Dc, 0, lmw, Dc, 0, (float*)d_out, Vc, 0, nullptr, Dc, 1.0f);
}

// Round 4
// 1298.277 us; speedup vs baseline: 1.3364x; 1.2297x over previous
//
#include <hip/hip_runtime.h>
#include <hip/hip_bf16.h>
#include <math.h>

typedef __hip_bfloat16 bf16;
typedef __attribute__((ext_vector_type(4))) float f32x4;
typedef __attribute__((ext_vector_type(8))) short short8;

constexpr int Bc = 2, Tc = 1024, Dc = 1024, Hc = 16, Lc = 4, MLPc = 4096, Vc = 32000, HDc = 64;

__device__ __forceinline__ unsigned short f2bu(float f) {
    __hip_bfloat16 h = __float2bfloat16(f);
    unsigned short u;
    __builtin_memcpy(&u, &h, 2);
    return u;
}

__device__ __forceinline__ void gl2lds16(const bf16* g, bf16* l) {
    __builtin_amdgcn_global_load_lds(
        (const __attribute__((address_space(1))) void*)g,
        (__attribute__((address_space(3))) void*)l, 16, 0, 0);
}

enum { EPI_BIAS_BF16 = 0, EPI_GELU = 1, EPI_RESADD = 2, EPI_F32 = 3 };

template <int EPI>
__device__ __forceinline__ void epi_store(float v, int row, int col, void* Cv,
                                          int ldc, const float* bias) {
    if constexpr (EPI == EPI_BIAS_BF16) {
        v += bias[col];
        ((bf16*)Cv)[(size_t)row * ldc + col] = __float2bfloat16(v);
    } else if constexpr (EPI == EPI_GELU) {
        v += bias[col];
        v = 0.5f * v * (1.0f + erff(v * 0.70710678118f));
        ((bf16*)Cv)[(size_t)row * ldc + col] = __float2bfloat16(v);
    } else if constexpr (EPI == EPI_RESADD) {
        float* C = (float*)Cv;
        size_t idx = (size_t)row * ldc + col;
        C[idx] += v + bias[col];
    } else if constexpr (EPI == EPI_F32) {
        ((float*)Cv)[(size_t)row * ldc + col] = v;
    }
}

// ---------- weight GEMM: A,B bf16, global_load_lds + T2 swizzle + T1 grid swizzle ----------
template <int BM, int BN, int BK, int EPI, bool SWZG>
__global__ __launch_bounds__(256) void gemm_fast(
    const bf16* __restrict__ A, int lda,
    const bf16* __restrict__ Bm, int ldb,
    void* __restrict__ Cv, int ldc,
    const float* __restrict__ bias, int K)
{
    static_assert(BK == 64, "staging geometry assumes BK=64");
    __shared__ alignas(16) bf16 As[BM][BK];
    __shared__ alignas(16) bf16 Bs[BN][BK];

    const int tid = threadIdx.x;
    const int lane = tid & 63;
    const int w = tid >> 6;
    const int wm = w >> 1, wn = w & 1;
    constexpr int WM = BM / 2, WN = BN / 2;
    constexpr int FM = WM / 16, FN = WN / 16;
    constexpr int RPI = 512 / BK;
    constexpr int AI = BM / (4 * RPI);
    constexpr int BI = BN / (4 * RPI);

    int im, in;
    if constexpr (SWZG) {
        int nwg = gridDim.x * gridDim.y;
        int orig = blockIdx.y * gridDim.x + blockIdx.x;
        int q = nwg >> 3, rr = nwg & 7, xcd = orig & 7, lid = orig >> 3;
        int wg = (xcd < rr ? xcd * (q + 1) : rr * (q + 1) + (xcd - rr) * q) + lid;
        im = wg % gridDim.x;
        in = wg / gridDim.x;
    } else {
        im = blockIdx.y;
        in = blockIdx.x;
    }

    const bf16* Ab = A + (size_t)im * BM * lda;
    const bf16* Bb = Bm + (size_t)in * BN * ldb;

    const int sr = lane >> 3;
    const int scs = (((lane & 7) ^ sr) * 8);
    const int lr = lane & 15, lq = lane >> 4;

    f32x4 acc[FM][FN];
#pragma unroll
    for (int i = 0; i < FM; i++)
#pragma unroll
        for (int j = 0; j < FN; j++) acc[i][j] = (f32x4){0.f, 0.f, 0.f, 0.f};

    for (int k0 = 0; k0 < K; k0 += BK) {
#pragma unroll
        for (int i = 0; i < AI; i++) {
            int row = (w * AI + i) * RPI;
            gl2lds16(Ab + (size_t)(row + sr) * lda + k0 + scs, &As[row][0]);
        }
#pragma unroll
        for (int i = 0; i < BI; i++) {
            int row = (w * BI + i) * RPI;
            gl2lds16(Bb + (size_t)(row + sr) * ldb + k0 + scs, &Bs[row][0]);
        }
        __syncthreads();

#pragma unroll
        for (int kk = 0; kk < BK / 32; kk++) {
            short8 af[FM], bfr[FN];
#pragma unroll
            for (int i = 0; i < FM; i++) {
                int r = wm * WM + i * 16 + lr;
                int cb = (kk * 64 + lq * 16) ^ ((r & 7) << 4);
                af[i] = *reinterpret_cast<const short8*>((const char*)As + (size_t)r * (BK * 2) + cb);
            }
#pragma unroll
            for (int j = 0; j < FN; j++) {
                int r = wn * WN + j * 16 + lr;
                int cb = (kk * 64 + lq * 16) ^ ((r & 7) << 4);
                bfr[j] = *reinterpret_cast<const short8*>((const char*)Bs + (size_t)r * (BK * 2) + cb);
            }
#pragma unroll
            for (int i = 0; i < FM; i++)
#pragma unroll
                for (int j = 0; j < FN; j++)
                    acc[i][j] = __builtin_amdgcn_mfma_f32_16x16x32_bf16(af[i], bfr[j], acc[i][j], 0, 0, 0);
        }
        __syncthreads();
    }

#pragma unroll
    for (int i = 0; i < FM; i++)
#pragma unroll
        for (int j = 0; j < FN; j++)
#pragma unroll
            for (int r = 0; r < 4; r++) {
                int row = im * BM + wm * WM + i * 16 + lq * 4 + r;
                int col = in * BN + wn * WN + j * 16 + lr;
                epi_store<EPI>(acc[i][j][r], row, col, Cv, ldc, bias);
            }
}

// ---------- flash attention: online softmax, no S/P materialization ----------
// grid (16 q-tiles, 32 bh), 256 thr = 4 waves x 16 q-rows. KV tile = 128.
__global__ __launch_bounds__(256) void flash_attn(
    const bf16* __restrict__ q, const bf16* __restrict__ kbuf,
    const bf16* __restrict__ vt, bf16* __restrict__ y)
{
    __shared__ alignas(16) bf16 Ks[128 * 64];    // [kvrow][d]
    __shared__ alignas(16) bf16 Vs[64 * 128];    // [d][kvcol]
    __shared__ alignas(16) bf16 Ps[4 * 16 * 136]; // per-wave [qrow][kvcol], padded

    const int tid = threadIdx.x;
    const int lane = tid & 63;
    const int w = tid >> 6;
    const int lr = lane & 15, lq = lane >> 4;
    const int qi = (int)gridDim.x - 1 - (int)blockIdx.x;  // big tiles first
    const int z = blockIdx.y;
    const int b = z >> 4, h = z & 15;
    const float slope = exp2f(-0.5f * (float)(h + 1));

    const bf16* qz = q + (size_t)z * (Tc * HDc);
    const bf16* kz = kbuf + (size_t)z * (Tc * HDc);
    const bf16* vz = vt + (size_t)z * (HDc * Tc);

    const int rowbase = qi * 64 + w * 16;

    // Q fragment (A-operand): row=lr, k = kk*32 + lq*8
    short8 qf[2];
#pragma unroll
    for (int kk = 0; kk < 2; kk++)
        qf[kk] = *reinterpret_cast<const short8*>(
            qz + (size_t)(rowbase + lr) * HDc + kk * 32 + lq * 8);

    float m_old[4], l_sum[4];
#pragma unroll
    for (int r = 0; r < 4; r++) { m_old[r] = -3.0e38f; l_sum[r] = 0.f; }
    f32x4 o[4];
#pragma unroll
    for (int dj = 0; dj < 4; dj++) o[dj] = (f32x4){0.f, 0.f, 0.f, 0.f};

    bf16* Pw = Ps + w * 16 * 136;

    const int nkv = (qi * 64 + 63) / 128 + 1;
    for (int kv = 0; kv < nkv; kv++) {
        // ---- stage K tile [128][64]: 8 rows per instr, XOR-swizzled source ----
#pragma unroll
        for (int i = 0; i < 4; i++) {
            int rbase = w * 32 + i * 8;
            int row = rbase + (lane >> 3);
            int slot = lane & 7;
            gl2lds16(kz + (size_t)(kv * 128 + row) * HDc + ((slot ^ (row & 7)) * 8),
                     &Ks[rbase * 64]);
        }
        // ---- stage V^T tile [64][128]: 4 rows per instr ----
#pragma unroll
        for (int i = 0; i < 4; i++) {
            int rbase = w * 16 + i * 4;
            int row = rbase + lq;
            gl2lds16(vz + (size_t)row * Tc + kv * 128 + ((lr ^ (row & 7)) * 8),
                     &Vs[rbase * 128]);
        }
        __syncthreads();

        // ---- S = Q K^T ----
        f32x4 s[8];
#pragma unroll
        for (int j = 0; j < 8; j++) s[j] = (f32x4){0.f, 0.f, 0.f, 0.f};
#pragma unroll
        for (int kk = 0; kk < 2; kk++) {
#pragma unroll
            for (int j = 0; j < 8; j++) {
                int row = j * 16 + lr;
                int cb = ((kk * 4 + lq) ^ (row & 7)) << 4;
                short8 bfr = *reinterpret_cast<const short8*>(
                    (const char*)Ks + row * 128 + cb);
                s[j] = __builtin_amdgcn_mfma_f32_16x16x32_bf16(qf[kk], bfr, s[j], 0, 0, 0);
            }
        }

        // ---- bias + causal mask, running max ----
        float mt[4];
#pragma unroll
        for (int r = 0; r < 4; r++) mt[r] = -3.0e38f;
#pragma unroll
        for (int j = 0; j < 8; j++) {
            int col = kv * 128 + j * 16 + lr;
#pragma unroll
            for (int r = 0; r < 4; r++) {
                int rowg = rowbase + lq * 4 + r;
                float v = s[j][r] * 0.125f - (float)(rowg - col) * slope;
                v = (col > rowg) ? -3.0e38f : v;
                s[j][r] = v;
                mt[r] = fmaxf(mt[r], v);
            }
        }
#pragma unroll
        for (int r = 0; r < 4; r++)
#pragma unroll
            for (int off = 1; off < 16; off <<= 1)
                mt[r] = fmaxf(mt[r], __shfl_xor(mt[r], off));

        float f[4], rs[4];
#pragma unroll
        for (int r = 0; r < 4; r++) {
            float mn = fmaxf(m_old[r], mt[r]);
            f[r] = __expf(m_old[r] - mn);
            m_old[r] = mn;
            rs[r] = 0.f;
        }
#pragma unroll
        for (int j = 0; j < 8; j++)
#pragma unroll
            for (int r = 0; r < 4; r++) {
                float p = __expf(s[j][r] - m_old[r]);
                s[j][r] = p;
                rs[r] += p;
            }
#pragma unroll
        for (int r = 0; r < 4; r++) {
#pragma unroll
            for (int off = 1; off < 16; off <<= 1)
                rs[r] += __shfl_xor(rs[r], off);
            l_sum[r] = l_sum[r] * f[r] + rs[r];
        }

        // ---- P -> LDS (per-wave region, padded rows: conflict-free reads) ----
#pragma unroll
        for (int j = 0; j < 8; j++)
#pragma unroll
            for (int r = 0; r < 4; r++)
                Pw[(lq * 4 + r) * 136 + j * 16 + lr] = __float2bfloat16(s[j][r]);

        // ---- rescale O ----
#pragma unroll
        for (int dj = 0; dj < 4; dj++)
#pragma unroll
            for (int r = 0; r < 4; r++) o[dj][r] *= f[r];

        __syncthreads();

        // ---- O += P V ----
#pragma unroll
        for (int kk = 0; kk < 4; kk++) {
            short8 pa = *reinterpret_cast<const short8*>(
                (const char*)Pw + lr * 272 + kk * 64 + lq * 16);
#pragma unroll
            for (int dj = 0; dj < 4; dj++) {
                int row = dj * 16 + lr;
                int cb = ((kk * 4 + lq) ^ (row & 7)) << 4;
                short8 vb = *reinterpret_cast<const short8*>(
                    (const char*)Vs + row * 256 + cb);
                o[dj] = __builtin_amdgcn_mfma_f32_16x16x32_bf16(pa, vb, o[dj], 0, 0, 0);
            }
        }
        __syncthreads();
    }

    // ---- epilogue: normalize, write y[b][t][h*64+d] ----
#pragma unroll
    for (int dj = 0; dj < 4; dj++)
#pragma unroll
        for (int r = 0; r < 4; r++) {
            int rowg = rowbase + lq * 4 + r;
            float outv = o[dj][r] / l_sum[r];
            y[((size_t)b * Tc + rowg) * Dc + h * HDc + dj * 16 + lr] =
                __float2bfloat16(outv);
        }
}

__global__ __launch_bounds__(256) void f2b8(const float* __restrict__ in,
                                            bf16* __restrict__ out, long n) {
    long i = ((long)blockIdx.x * 256 + threadIdx.x) * 8;
    if (i >= n) return;
    float4 a = *reinterpret_cast<const float4*>(in + i);
    float4 b = *reinterpret_cast<const float4*>(in + i + 4);
    unsigned long long p0 = (unsigned long long)f2bu(a.x) |
                            ((unsigned long long)f2bu(a.y) << 16) |
                            ((unsigned long long)f2bu(a.z) << 32) |
                            ((unsigned long long)f2bu(a.w) << 48);
    unsigned long long p1 = (unsigned long long)f2bu(b.x) |
                            ((unsigned long long)f2bu(b.y) << 16) |
                            ((unsigned long long)f2bu(b.z) << 32) |
                            ((unsigned long long)f2bu(b.w) << 48);
    *reinterpret_cast<unsigned long long*>(out + i) = p0;
    *reinterpret_cast<unsigned long long*>(out + i + 4) = p1;
}

__global__ __launch_bounds__(256) void embed_kernel(const int* __restrict__ ids,
                                                    const float* __restrict__ wte,
                                                    float* __restrict__ x) {
    int row = blockIdx.x;
    int t = threadIdx.x;
    int id = ids[row];
    reinterpret_cast<float4*>(x + (size_t)row * Dc)[t] =
        reinterpret_cast<const float4*>(wte + (size_t)id * Dc)[t];
}

__global__ __launch_bounds__(256) void ln_kernel(const float* __restrict__ x,
                                                 const float* __restrict__ g,
                                                 const float* __restrict__ b,
                                                 bf16* __restrict__ out) {
    int row = blockIdx.x;
    int t = threadIdx.x;
    const float4 v = reinterpret_cast<const float4*>(x + (size_t)row * Dc)[t];
    float s = v.x + v.y + v.z + v.w;
    float s2 = v.x * v.x + v.y * v.y + v.z * v.z + v.w * v.w;
#pragma unroll
    for (int o = 32; o > 0; o >>= 1) {
        s += __shfl_down(s, o);
        s2 += __shfl_down(s2, o);
    }
    __shared__ float sm[8];
    int wid = t >> 6, ln = t & 63;
    if (ln == 0) { sm[wid] = s; sm[4 + wid] = s2; }
    __syncthreads();
    if (t == 0) {
        float ts = sm[0] + sm[1] + sm[2] + sm[3];
        float ts2 = sm[4] + sm[5] + sm[6] + sm[7];
        sm[0] = ts; sm[4] = ts2;
    }
    __syncthreads();
    float mean = sm[0] * (1.0f / Dc);
    float var = sm[4] * (1.0f / Dc) - mean * mean;
    float rstd = rsqrtf(var + 1e-5f);
    int c0 = t * 4;
    float vv[4] = {v.x, v.y, v.z, v.w};
    unsigned long long p = 0;
#pragma unroll
    for (int j = 0; j < 4; j++) {
        float val = (vv[j] - mean) * rstd * g[c0 + j] + b[c0 + j];
        p |= (unsigned long long)f2bu(val) << (16 * j);
    }
    *reinterpret_cast<unsigned long long*>(out + (size_t)row * Dc + c0) = p;
}

__global__ __launch_bounds__(256) void unpack_qk(const bf16* __restrict__ qkv,
                                                 bf16* __restrict__ q,
                                                 bf16* __restrict__ k) {
    int idx = blockIdx.x * 256 + threadIdx.x;
    int bt = idx / 128;
    int c = idx % 128;
    int b = bt / Tc, t = bt % Tc;
    int h = c >> 3;
    int hd = (c & 7) * 8;
    size_t dst = (((size_t)(b * Hc + h) * Tc + t) * HDc + hd) / 8;
    const int4* src = reinterpret_cast<const int4*>(qkv + (size_t)bt * 3 * Dc);
    reinterpret_cast<int4*>(q)[dst] = src[c];
    reinterpret_cast<int4*>(k)[dst] = src[128 + c];
}

__global__ __launch_bounds__(256) void unpack_vt(const bf16* __restrict__ qkv,
                                                 bf16* __restrict__ vt) {
    int idx = blockIdx.x * 256 + threadIdx.x;
    int t = idx & (Tc - 1);
    int rest = idx >> 10;
    int hd = rest & 63;
    int zh = rest >> 6;
    int b = zh >> 4, h = zh & 15;
    vt[idx] = qkv[((size_t)(b * Tc + t)) * 3 * Dc + 2 * Dc + h * HDc + hd];
}

extern "C" void kernel_launch(void* const* d_in, const int* in_sizes, int n_in,
                              void* d_out, int out_size, void* d_ws, size_t ws_size,
                              hipStream_t stream) {
    const int* ids = (const int*)d_in[0];
    const float* wte = (const float*)d_in[1];
    const float* ln1g = (const float*)d_in[2];
    const float* ln1b = (const float*)d_in[3];
    const float* attw = (const float*)d_in[4];
    const float* attb = (const float*)d_in[5];
    const float* projw = (const float*)d_in[6];
    const float* projb = (const float*)d_in[7];
    const float* ln2g = (const float*)d_in[8];
    const float* ln2b = (const float*)d_in[9];
    const float* fcw = (const float*)d_in[10];
    const float* fcb = (const float*)d_in[11];
    const float* fc2w = (const float*)d_in[12];
    const float* fc2b = (const float*)d_in[13];
    const float* lnfg = (const float*)d_in[14];
    const float* lnfb = (const float*)d_in[15];
    const float* lmw = (const float*)d_in[16];

    const int M = Bc * Tc;  // 2048
    char* ws = (char*)d_ws;
    size_t off = 0;
    auto carve = [&](size_t bytes) { char* p = ws + off; off += (bytes + 255) & ~(size_t)255; return p; };

    float* x = (float*)carve((size_t)M * Dc * 4);
    bf16* h = (bf16*)carve((size_t)M * Dc * 2);
    bf16* qkv = (bf16*)carve((size_t)M * 3 * Dc * 2);
    bf16* q = (bf16*)carve((size_t)Bc * Hc * Tc * HDc * 2);
    bf16* kb = (bf16*)carve((size_t)Bc * Hc * Tc * HDc * 2);
    bf16* vt = (bf16*)carve((size_t)Bc * Hc * Tc * HDc * 2);
    bf16* y = (bf16*)carve((size_t)M * Dc * 2);
    bf16* mlp = (bf16*)carve((size_t)M * MLPc * 2);
    size_t base_end = off;

    const long nWL = (long)3 * Dc * Dc + (long)Dc * Dc + (long)MLPc * Dc + (long)Dc * MLPc;
    const long nLM = (long)Vc * Dc;
    bool has_wl = ws_size >= base_end + (size_t)nWL * 2;
    bf16* wl = nullptr;
    if (has_wl) wl = (bf16*)carve((size_t)nWL * 2);
    bool has_wlm = has_wl && ws_size >= off + (size_t)nLM * 2;
    bf16* wlm = nullptr;
    if (has_wlm) wlm = (bf16*)carve((size_t)nLM * 2);

    bf16* aw_b = wl;
    bf16* pw_b = wl ? wl + (size_t)3 * Dc * Dc : nullptr;
    bf16* fw_b = pw_b ? pw_b + (size_t)Dc * Dc : nullptr;
    bf16* f2w_b = fw_b ? fw_b + (size_t)MLPc * Dc : nullptr;

    embed_kernel<<<M, 256, 0, stream>>>(ids, wte, x);

    if (has_wlm)
        f2b8<<<(int)(nLM / 8 / 256), 256, 0, stream>>>(lmw, wlm, nLM);
    if (!has_wl) {
        // shouldn't happen given harness workspace, but keep deterministic:
        // fall back to converting into the base region repeatedly is unsafe;
        // instead reuse mlp buffer per-GEMM is insufficient -> just convert
        // lm_head into d_out? Simplest: treat as has_wl with aliased buffers
        // is invalid; we rely on ws_size (checked) being large enough.
    }

    for (int l = 0; l < Lc; l++) {
        if (has_wl) {
            f2b8<<<(int)((long)3 * Dc * Dc / 8 / 256), 256, 0, stream>>>(
                attw + (size_t)l * 3 * Dc * Dc, aw_b, (long)3 * Dc * Dc);
            f2b8<<<(int)((long)Dc * Dc / 8 / 256), 256, 0, stream>>>(
                projw + (size_t)l * Dc * Dc, pw_b, (long)Dc * Dc);
            f2b8<<<(int)((long)MLPc * Dc / 8 / 256), 256, 0, stream>>>(
                fcw + (size_t)l * MLPc * Dc, fw_b, (long)MLPc * Dc);
            f2b8<<<(int)((long)Dc * MLPc / 8 / 256), 256, 0, stream>>>(
                fc2w + (size_t)l * Dc * MLPc, f2w_b, (long)Dc * MLPc);
        }

        ln_kernel<<<M, 256, 0, stream>>>(x, ln1g + l * Dc, ln1b + l * Dc, h);

        gemm_fast<128, 128, 64, EPI_BIAS_BF16, true>
            <<<dim3(M / 128, 3 * Dc / 128, 1), 256, 0, stream>>>(
                h, Dc, aw_b, Dc, qkv, 3 * Dc, attb + l * 3 * Dc, Dc);

        unpack_qk<<<(M * Dc / 8) / 256, 256, 0, stream>>>(qkv, q, kb);
        unpack_vt<<<(Bc * Hc * HDc * Tc) / 256, 256, 0, stream>>>(qkv, vt);

        flash_attn<<<dim3(Tc / 64, Bc * Hc), 256, 0, stream>>>(q, kb, vt, y);

        gemm_fast<128, 128, 64, EPI_RESADD, true>
            <<<dim3(M / 128, Dc / 128, 1), 256, 0, stream>>>(
                y, Dc, pw_b, Dc, x, Dc, projb + l * Dc, Dc);

        ln_kernel<<<M, 256, 0, stream>>>(x, ln2g + l * Dc, ln2b + l * Dc, h);

        gemm_fast<128, 128, 64, EPI_GELU, true>
            <<<dim3(M / 128, MLPc / 128, 1), 256, 0, stream>>>(
                h, Dc, fw_b, Dc, mlp, MLPc, fcb + l * MLPc, Dc);

        gemm_fast<128, 128, 64, EPI_RESADD, true>
            <<<dim3(M / 128, Dc / 128, 1), 256, 0, stream>>>(
                mlp, MLPc, f2w_b, MLPc, x, Dc, fc2b + l * Dc, MLPc);
    }

    ln_kernel<<<M, 256, 0, stream>>>(x, lnfg, lnfb, h);

    gemm_fast<128, 128, 64, EPI_F32, true>
        <<<dim3(M / 128, Vc / 128, 1), 256, 0, stream>>>(
            h, Dc, wlm, Dc, (float*)d_out, Vc, nullptr, Dc);
}